// Round 6
// baseline (10512.530 us; speedup 1.0000x reference)
//
#include <hip/hip_runtime.h>

// Inputs/outputs are float32 (reference setup_inputs uses jnp.float32).
// Quantized values are small integers; int math in int32 (exact), scales in fp32.

__global__ void Bottleneck_61022895341826_kernel() {}  // keep stub symbol

__global__ void k_probe(float* out, int n) {
    int i = blockIdx.x * blockDim.x + threadIdx.x;
    int stride = gridDim.x * blockDim.x;
    for (int j = i; j < n; j += stride) out[j] = 1.0f;
}

// one block: max|w| -> *sc
__global__ void k_scale(const float* w, int n, float* sc) {
    __shared__ float red[256];
    float m = 0.0f;
    for (int i = threadIdx.x; i < n; i += 256) m = fmaxf(m, fabsf(w[i]));
    red[threadIdx.x] = m;
    __syncthreads();
    for (int s = 128; s > 0; s >>= 1) {
        if (threadIdx.x < s) red[threadIdx.x] = fmaxf(red[threadIdx.x], red[threadIdx.x + s]);
        __syncthreads();
    }
    if (threadIdx.x == 0) sc[0] = red[0];
}

__global__ void k_quant8(const float* w, const float* sc, signed char* o, int n) {
    float s = sc[0];
    int i = blockIdx.x * blockDim.x + threadIdx.x;
    int stride = gridDim.x * blockDim.x;
    for (int j = i; j < n; j += stride) {
        float v = w[j] / s;
        v = fminf(fmaxf(v, -1.0f), 1.0f);
        o[j] = (signed char)(int)rintf(v * 127.0f);
    }
}

__global__ void k_quantb(const float* b, float* o, int n) {
    int i = blockIdx.x * blockDim.x + threadIdx.x;
    if (i < n) o[i] = rintf(b[i] * 127.0f);
}

__global__ void k_quantx(const float* x, signed char* o, int n) {
    int i = blockIdx.x * blockDim.x + threadIdx.x;
    int stride = gridDim.x * blockDim.x;
    for (int j = i; j < n; j += stride) {
        float v = x[j] * 2.0f;
        v = fminf(fmaxf(v, -1.0f), 1.0f);
        o[j] = (signed char)(int)rintf(v * 127.0f);
    }
}

// conv1 1x1: a1[b][p][hw] over K=512, then scaled ReLU6 + requant to int8
__global__ void k_conv1(const signed char* xq, const signed char* w1q,
                        const float* sc, const float* bi1, signed char* a1) {
    int idx = blockIdx.x * blockDim.x + threadIdx.x;
    if (idx >= 64 * 256 * 784) return;
    int hw = idx % 784;
    int p  = (idx / 784) % 256;
    int b  = idx / (784 * 256);
    const signed char* xb = xq + (size_t)b * 512 * 784 + hw;
    const signed char* wp = w1q + (size_t)p * 512;
    int s = 0;
    for (int c = 0; c < 512; c++) s += (int)xb[(size_t)c * 784] * (int)wp[c];
    float v = sc[0] * (float)s / 16129.0f + bi1[p] * (2.0f / 127.0f);
    float q = rintf(127.0f * fminf(fmaxf(2.0f * v, 0.0f), 1.0f));
    a1[idx] = (signed char)(int)q;
}

// conv2 3x3 stride2 pad1: a2[b][p][oh][ow]
__global__ void k_conv2(const signed char* a1, const signed char* w2q,
                        const float* sc, const float* bi2, signed char* a2) {
    int idx = blockIdx.x * blockDim.x + threadIdx.x;
    if (idx >= 64 * 256 * 196) return;
    int ow = idx % 14;
    int oh = (idx / 14) % 14;
    int p  = (idx / 196) % 256;
    int b  = idx / (196 * 256);
    const signed char* ab = a1 + (size_t)b * 256 * 784;
    const signed char* wp = w2q + (size_t)p * 256 * 9;
    int s = 0;
    for (int c = 0; c < 256; c++) {
        const signed char* ac = ab + (size_t)c * 784;
        const signed char* wc = wp + c * 9;
        for (int kh = 0; kh < 3; kh++) {
            int ih = 2 * oh - 1 + kh;
            if (ih < 0 || ih >= 28) continue;
            for (int kw = 0; kw < 3; kw++) {
                int iw = 2 * ow - 1 + kw;
                if (iw < 0 || iw >= 28) continue;
                s += (int)ac[ih * 28 + iw] * (int)wc[kh * 3 + kw];
            }
        }
    }
    float v = sc[1] * (float)s / 16129.0f + bi2[p] * (2.0f / 127.0f);
    float q = rintf(127.0f * fminf(fmaxf(2.0f * v, 0.0f), 1.0f));
    a2[idx] = (signed char)(int)q;
}

// conv3 1x1 + downsample shortcut 1x1 stride2 + final relu6 -> float NCHW out
// final clamp is NaN-PROPAGATING on purpose (diagnostic: garbage -> NaN, not 0)
__global__ void k_conv3(const signed char* xq, const signed char* a2,
                        const signed char* w3q, const signed char* wsq,
                        const float* sc, const float* bi3, const float* bis,
                        float* out) {
    int idx = blockIdx.x * blockDim.x + threadIdx.x;
    if (idx >= 64 * 1024 * 196) return;
    int hw = idx % 196;
    int o  = (idx / 196) % 1024;
    int b  = idx / (196 * 1024);
    int oh = hw / 14, ow = hw % 14;
    const signed char* ab = a2 + (size_t)b * 256 * 196 + hw;
    const signed char* w3p = w3q + (size_t)o * 256;
    int s3 = 0;
    for (int c = 0; c < 256; c++) s3 += (int)ab[(size_t)c * 196] * (int)w3p[c];
    int ps = (2 * oh) * 28 + 2 * ow;
    const signed char* xb = xq + (size_t)b * 512 * 784 + ps;
    const signed char* wsp = wsq + (size_t)o * 512;
    int ss = 0;
    for (int c = 0; c < 512; c++) ss += (int)xb[(size_t)c * 784] * (int)wsp[c];
    float c2 = sc[1], c3 = sc[2], cs = sc[3];
    float v = 0.5f * (c3 * (float)s3 + cs * (float)ss) / 16129.0f
            + bi3[o] * (c3 / (127.0f * c2)) + bis[o] * (1.0f / 127.0f);
    v = v < 0.0f ? 0.0f : (v > 6.0f ? 6.0f : v);   // NaN-propagating clip
    out[idx] = v;
}

extern "C" void kernel_launch(void* const* d_in, const int* in_sizes, int n_in,
                              void* d_out, int out_size, void* d_ws, size_t ws_size,
                              hipStream_t stream) {
    const float* x   = (const float*)d_in[0];
    const float* w1  = (const float*)d_in[1];
    const float* b1  = (const float*)d_in[2];
    const float* w2  = (const float*)d_in[3];
    const float* b2  = (const float*)d_in[4];
    const float* w3  = (const float*)d_in[5];
    const float* b3  = (const float*)d_in[6];
    const float* wsd = (const float*)d_in[7];
    const float* bs  = (const float*)d_in[8];
    float* out = (float*)d_out;
    char* ws = (char*)d_ws;

    float* sc  = (float*)ws;                 // 4 scales
    float* bi1 = (float*)(ws + 1024);
    float* bi2 = (float*)(ws + 2048);
    float* bi3 = (float*)(ws + 4096);
    float* bis = (float*)(ws + 8192);
    signed char* w1q = (signed char*)(ws + 16384);
    signed char* w2q = w1q + 131072;
    signed char* w3q = w2q + 589824;
    signed char* wsq = w3q + 262144;
    signed char* xq  = (signed char*)(ws + 1572864);
    signed char* a1  = xq + 25690112;        // 64*512*784
    signed char* a2  = a1 + 12845056;        // 64*256*784 ; a2: 64*256*196

    k_probe<<<512, 256, 0, stream>>>(out, out_size);

    k_scale<<<1, 256, 0, stream>>>(w1, 131072, sc + 0);
    k_scale<<<1, 256, 0, stream>>>(w2, 589824, sc + 1);
    k_scale<<<1, 256, 0, stream>>>(w3, 262144, sc + 2);
    k_scale<<<1, 256, 0, stream>>>(wsd, 524288, sc + 3);

    k_quant8<<<512, 256, 0, stream>>>(w1, sc + 0, w1q, 131072);
    k_quant8<<<512, 256, 0, stream>>>(w2, sc + 1, w2q, 589824);
    k_quant8<<<512, 256, 0, stream>>>(w3, sc + 2, w3q, 262144);
    k_quant8<<<512, 256, 0, stream>>>(wsd, sc + 3, wsq, 524288);

    k_quantb<<<1, 256, 0, stream>>>(b1, bi1, 256);
    k_quantb<<<1, 256, 0, stream>>>(b2, bi2, 256);
    k_quantb<<<4, 256, 0, stream>>>(b3, bi3, 1024);
    k_quantb<<<4, 256, 0, stream>>>(bs, bis, 1024);

    k_quantx<<<4096, 256, 0, stream>>>(x, xq, 25690112);

    k_conv1<<<50176, 256, 0, stream>>>(xq, w1q, sc, bi1, a1);
    k_conv2<<<12544, 256, 0, stream>>>(a1, w2q, sc, bi2, a2);
    k_conv3<<<50176, 256, 0, stream>>>(xq, a2, w3q, wsq, sc, bi3, bis, out);
}

// Round 7
// 471.789 us; speedup vs baseline: 22.2823x; 22.2823x over previous
//
#include <hip/hip_runtime.h>
#include <stdint.h>

typedef int int4v __attribute__((ext_vector_type(4)));

// ---- workspace layout (bytes). High water ~43.8 MB (round 6 proved >=43.3 works)
#define WS_SCALES 0ull
#define WS_ZERO   256ull          // int8 zero page
#define WS_BI1    1024ull
#define WS_BI2    2048ull
#define WS_BI3    4096ull
#define WS_BIS    8192ull
#define WS_W1Q    16384ull                     // int8 [256][512]
#define WS_W2Q    (WS_W1Q + 131072ull)         // int8 [256][2304]  k = (kh*3+kw)*256 + c
#define WS_W3Q    (WS_W2Q + 589824ull)         // int8 [1024][256]
#define WS_WSQ    (WS_W3Q + 262144ull)         // int8 [1024][512]
#define WS_A0     2097152ull                   // int8 [64][784][512]
#define WS_A1     (WS_A0 + 25690112ull)        // int8 [64][784][256]
#define WS_A2     (WS_A1 + 12845056ull)        // int8 [64][196][256]

__global__ void k_init(float* wshead) {
    int i = blockIdx.x * 256 + threadIdx.x;   // 16 blocks x 256 = 4096 floats = 16KB
    wshead[i] = 0.0f;
}

// grid (32, 4): per-tensor max|w| via atomicMax on float bits (all positive)
__global__ void k_maxabs(const float* __restrict__ w1, const float* __restrict__ w2,
                         const float* __restrict__ w3, const float* __restrict__ wsd,
                         float* __restrict__ scales) {
    const float* srcs[4] = {w1, w2, w3, wsd};
    const int ns[4] = {131072, 589824, 262144, 524288};
    int t = blockIdx.y;
    const float* s = srcs[t];
    int n = ns[t];
    float m = 0.0f;
    for (int i = blockIdx.x * 256 + threadIdx.x; i < n; i += gridDim.x * 256)
        m = fmaxf(m, fabsf(s[i]));
    __shared__ float red[256];
    red[threadIdx.x] = m;
    __syncthreads();
    for (int st = 128; st > 0; st >>= 1) {
        if (threadIdx.x < st) red[threadIdx.x] = fmaxf(red[threadIdx.x], red[threadIdx.x + st]);
        __syncthreads();
    }
    if (threadIdx.x == 0) atomicMax((int*)&scales[t], __float_as_int(red[0]));
}

// quantize weights to int8 (w2 reordered), biases to round(b*127) float
__global__ void k_quant_w(const float* __restrict__ w1, const float* __restrict__ w2,
                          const float* __restrict__ w3, const float* __restrict__ wsd,
                          const float* __restrict__ b1, const float* __restrict__ b2,
                          const float* __restrict__ b3, const float* __restrict__ bs,
                          char* __restrict__ wsb) {
    const float* sc = (const float*)(wsb + WS_SCALES);
    int mode = blockIdx.y;
    int i0 = blockIdx.x * 256 + threadIdx.x;
    int stride = gridDim.x * 256;
    if (mode == 0) {
        float s = sc[0]; signed char* o = (signed char*)(wsb + WS_W1Q);
        for (int i = i0; i < 131072; i += stride)
            o[i] = (signed char)(int)rintf(fminf(fmaxf(w1[i] / s, -1.f), 1.f) * 127.f);
    } else if (mode == 1) {
        float s = sc[1]; signed char* o = (signed char*)(wsb + WS_W2Q);
        for (int i = i0; i < 589824; i += stride) {
            int oo = i / 2304, r2 = i - oo * 2304;
            int c = r2 / 9, kk = r2 - c * 9;   // kk = kh*3+kw
            o[(size_t)oo * 2304 + kk * 256 + c] =
                (signed char)(int)rintf(fminf(fmaxf(w2[i] / s, -1.f), 1.f) * 127.f);
        }
    } else if (mode == 2) {
        float s = sc[2]; signed char* o = (signed char*)(wsb + WS_W3Q);
        for (int i = i0; i < 262144; i += stride)
            o[i] = (signed char)(int)rintf(fminf(fmaxf(w3[i] / s, -1.f), 1.f) * 127.f);
    } else if (mode == 3) {
        float s = sc[3]; signed char* o = (signed char*)(wsb + WS_WSQ);
        for (int i = i0; i < 524288; i += stride)
            o[i] = (signed char)(int)rintf(fminf(fmaxf(wsd[i] / s, -1.f), 1.f) * 127.f);
    } else if (mode == 4) {
        float* o = (float*)(wsb + WS_BI1);
        for (int i = i0; i < 256; i += stride) o[i] = rintf(b1[i] * 127.f);
    } else if (mode == 5) {
        float* o = (float*)(wsb + WS_BI2);
        for (int i = i0; i < 256; i += stride) o[i] = rintf(b2[i] * 127.f);
    } else if (mode == 6) {
        float* o = (float*)(wsb + WS_BI3);
        for (int i = i0; i < 1024; i += stride) o[i] = rintf(b3[i] * 127.f);
    } else {
        float* o = (float*)(wsb + WS_BIS);
        for (int i = i0; i < 1024; i += stride) o[i] = rintf(bs[i] * 127.f);
    }
}

// quantize + transpose x: float [64][512][784] -> int8 a0 [64][784][512]
__global__ void k_quant_x(const float* __restrict__ x, signed char* __restrict__ a0) {
    __shared__ signed char tile[32][33];
    int b = blockIdx.z;
    int p0 = blockIdx.x * 32, c0 = blockIdx.y * 32;
    int tp = threadIdx.x & 31, tr = threadIdx.x >> 5;
    const float* xb = x + ((size_t)b * 512 + c0) * 784 + p0;
    for (int i = 0; i < 4; i++) {
        int cc = tr + i * 8;
        float v = (p0 + tp < 784) ? xb[(size_t)cc * 784 + tp] : 0.f;
        v = fminf(fmaxf(v * 2.f, -1.f), 1.f);
        tile[cc][tp] = (signed char)(int)rintf(v * 127.f);
    }
    __syncthreads();
    signed char* ob = a0 + ((size_t)b * 784 + p0) * 512 + c0;
    for (int i = 0; i < 4; i++) {
        int pp = tr + i * 8;
        if (p0 + pp < 784) ob[(size_t)pp * 512 + tp] = tile[tp][pp];
    }
}

// ---------- i8-MFMA GEMM kernels (exact integer math) ----------
// MODE 0: conv1  M=256 K=512  N=784  -> a1 int8 [b][784][256]
// MODE 1: conv2  M=256 K=2304 N=196  implicit gemm 3x3/s2/p1 -> a2 int8 [b][196][256]
// MODE 2: conv3 (t<4: K=256 from a2) + shortcut (t>=4: K=512 from a0 strided), fused -> float out NCHW
template <int MODE, int BM, int BN, int WGM, int WGN>
__global__ __launch_bounds__(256) void k_conv(char* __restrict__ wsb, float* __restrict__ dout) {
    constexpr int FM = BM / WGM / 16;
    constexpr int FN = BN / WGN / 16;
    constexpr int ISS_A = BM / 16;
    constexpr int NISS = (BM + BN) / 16;
    constexpr int NI = NISS / 4;
    constexpr int KTOT = (MODE == 0) ? 512 : (MODE == 1) ? 2304 : 768;
    constexpr int NSTEP = KTOT / 64;           // 64 int8 k-values per step
    constexpr int NDIM = (MODE == 0) ? 784 : 196;

    __shared__ alignas(16) char lds[(BM + BN) * 64];   // row = 64 int8 k-values

    const int tid = threadIdx.x;
    const int wid = tid >> 6;
    const int lane = tid & 63;
    const int n0 = blockIdx.x * BN;
    const int m0 = blockIdx.y * BM;
    const int bb = blockIdx.z;

    const float* sc = (const float*)(wsb + WS_SCALES);
    const int srow = lane >> 2;    // staging row within 16-row issue
    const int schunk = lane & 3;   // 16B chunk = 16 k-values
    const int lrow = lane & 15;
    const int quad = lane >> 4;
    const int wm = (wid % WGM) * (BM / WGM);
    const int wn = (wid / WGM) * (BN / WGN);
    const char* zp = wsb + WS_ZERO + schunk * 16;

    int4v acc3[FM][FN] = {};   // MODE 0/1: the only accumulator; MODE 2: conv3 part
    int4v accS[FM][FN] = {};   // MODE 2: shortcut part

    for (int t = 0; t < NSTEP; ++t) {
        const int k0 = t * 64;
        uint4 stg[NI];
#pragma unroll
        for (int ii = 0; ii < NI; ii++) {
            const int s = wid + ii * 4;
            const char* g;
            if (s < ISS_A) {   // A = weights int8
                int m = m0 + s * 16 + srow;
                if (MODE == 0)
                    g = wsb + WS_W1Q + (size_t)m * 512 + k0 + schunk * 16;
                else if (MODE == 1)
                    g = wsb + WS_W2Q + (size_t)m * 2304 + k0 + schunk * 16;
                else
                    g = (k0 < 256) ? wsb + WS_W3Q + (size_t)m * 256 + k0 + schunk * 16
                                   : wsb + WS_WSQ + (size_t)m * 512 + (k0 - 256) + schunk * 16;
            } else {           // B = activations int8
                int n = n0 + (s - ISS_A) * 16 + srow;
                g = zp;
                if (MODE == 0) {
                    if (n < 784)
                        g = wsb + WS_A0 + ((size_t)bb * 784 + n) * 512 + k0 + schunk * 16;
                } else if (MODE == 1) {
                    if (n < 196) {
                        int oh = n / 14, ow = n - oh * 14;
                        int kk = k0 >> 8;              // 3x3 tap index (4 k-steps per tap)
                        int kh = kk / 3, kw = kk - kh * 3;
                        int c0 = k0 & 255;
                        int ih = 2 * oh - 1 + kh, iw = 2 * ow - 1 + kw;
                        if (ih >= 0 && ih < 28 && iw >= 0 && iw < 28)
                            g = wsb + WS_A1 + ((size_t)bb * 784 + ih * 28 + iw) * 256 + c0 + schunk * 16;
                    }
                } else {
                    if (n < 196) {
                        if (k0 < 256) {
                            g = wsb + WS_A2 + ((size_t)bb * 196 + n) * 256 + k0 + schunk * 16;
                        } else {
                            int oh = n / 14, ow = n - oh * 14;
                            int ps = oh * 56 + ow * 2;   // (2*oh)*28 + 2*ow
                            g = wsb + WS_A0 + ((size_t)bb * 784 + ps) * 512 + (k0 - 256) + schunk * 16;
                        }
                    }
                }
            }
            stg[ii] = *(const uint4*)g;
        }
        __syncthreads();   // prior iteration's LDS reads done
#pragma unroll
        for (int ii = 0; ii < NI; ii++) {
            const int s = wid + ii * 4;
            const int r = s * 16 + srow;
            const int pc = schunk ^ ((r >> 1) & 3);      // XOR swizzle
            *(uint4*)(lds + r * 64 + pc * 16) = stg[ii];
        }
        __syncthreads();

        int4v afr[FM], bfr[FN];
#pragma unroll
        for (int i = 0; i < FM; i++) {
            int m = wm + i * 16 + lrow;
            afr[i] = *(const int4v*)(lds + m * 64 + ((quad ^ ((m >> 1) & 3)) << 4));
        }
#pragma unroll
        for (int j = 0; j < FN; j++) {
            int n = wn + j * 16 + lrow;
            bfr[j] = *(const int4v*)(lds + (BM + n) * 64 + ((quad ^ ((n >> 1) & 3)) << 4));
        }
        if (MODE != 2 || t < 4) {
#pragma unroll
            for (int i = 0; i < FM; i++)
#pragma unroll
                for (int j = 0; j < FN; j++)
                    acc3[i][j] = __builtin_amdgcn_mfma_i32_16x16x64_i8(afr[i], bfr[j], acc3[i][j], 0, 0, 0);
        } else {
#pragma unroll
            for (int i = 0; i < FM; i++)
#pragma unroll
                for (int j = 0; j < FN; j++)
                    accS[i][j] = __builtin_amdgcn_mfma_i32_16x16x64_i8(afr[i], bfr[j], accS[i][j], 0, 0, 0);
        }
    }

    // ---------------- epilogue (C/D map: col=lane&15, row=quad*4+reg) ----------------
    if (MODE == 0 || MODE == 1) {
        const float alpha = sc[MODE] / 16129.0f;
        const float* bi = (const float*)(wsb + (MODE == 0 ? WS_BI1 : WS_BI2));
        signed char* outp = (signed char*)(wsb + (MODE == 0 ? WS_A1 : WS_A2)) + (size_t)bb * NDIM * 256;
#pragma unroll
        for (int i = 0; i < FM; i++) {
            int mb = m0 + wm + i * 16 + quad * 4;
            float bt[4];
#pragma unroll
            for (int r = 0; r < 4; r++) bt[r] = bi[mb + r] * (2.0f / 127.0f);
#pragma unroll
            for (int j = 0; j < FN; j++) {
                int n = n0 + wn + j * 16 + lrow;
                if (n < NDIM) {
                    unsigned pk = 0;
#pragma unroll
                    for (int r = 0; r < 4; r++) {
                        float v = alpha * (float)acc3[i][j][r] + bt[r];
                        int q = (int)rintf(127.0f * fminf(fmaxf(2.0f * v, 0.0f), 1.0f));
                        pk |= (unsigned)(q & 0xFF) << (8 * r);
                    }
                    *(unsigned*)(outp + (size_t)n * 256 + mb) = pk;
                }
            }
        }
    } else {
        const float c2 = sc[1], c3 = sc[2], cS = sc[3];
        const float* bi3 = (const float*)(wsb + WS_BI3);
        const float* bis = (const float*)(wsb + WS_BIS);
#pragma unroll
        for (int i = 0; i < FM; i++) {
            int mb = m0 + wm + i * 16 + quad * 4;
            float bt[4];
#pragma unroll
            for (int r = 0; r < 4; r++)
                bt[r] = bi3[mb + r] * (c3 / (127.0f * c2)) + bis[mb + r] * (1.0f / 127.0f);
#pragma unroll
            for (int j = 0; j < FN; j++) {
                int n = n0 + wn + j * 16 + lrow;
                if (n < 196) {
#pragma unroll
                    for (int r = 0; r < 4; r++) {
                        float v = (c3 * (float)acc3[i][j][r] + cS * (float)accS[i][j][r]) * (0.5f / 16129.0f) + bt[r];
                        v = v < 0.0f ? 0.0f : (v > 6.0f ? 6.0f : v);   // NaN-propagating
                        dout[((size_t)bb * 1024 + (mb + r)) * 196 + n] = v;
                    }
                }
            }
        }
    }
}

extern "C" void kernel_launch(void* const* d_in, const int* in_sizes, int n_in,
                              void* d_out, int out_size, void* d_ws, size_t ws_size,
                              hipStream_t stream) {
    const float* x   = (const float*)d_in[0];
    const float* w1  = (const float*)d_in[1];
    const float* b1  = (const float*)d_in[2];
    const float* w2  = (const float*)d_in[3];
    const float* b2  = (const float*)d_in[4];
    const float* w3  = (const float*)d_in[5];
    const float* b3  = (const float*)d_in[6];
    const float* wsd = (const float*)d_in[7];
    const float* bs  = (const float*)d_in[8];
    float* out = (float*)d_out;
    char* wsb = (char*)d_ws;

    k_init<<<16, 256, 0, stream>>>((float*)wsb);
    k_maxabs<<<dim3(32, 4), 256, 0, stream>>>(w1, w2, w3, wsd, (float*)(wsb + WS_SCALES));
    k_quant_w<<<dim3(96, 8), 256, 0, stream>>>(w1, w2, w3, wsd, b1, b2, b3, bs, wsb);
    k_quant_x<<<dim3(25, 16, 64), 256, 0, stream>>>(x, (signed char*)(wsb + WS_A0));
    k_conv<0, 128, 128, 2, 2><<<dim3(7, 2, 64), 256, 0, stream>>>(wsb, out);
    k_conv<1, 64, 128, 1, 4><<<dim3(2, 4, 64), 256, 0, stream>>>(wsb, out);
    k_conv<2, 128, 64, 2, 2><<<dim3(4, 8, 64), 256, 0, stream>>>(wsb, out);
}

// Round 8
// 469.519 us; speedup vs baseline: 22.3900x; 1.0048x over previous
//
#include <hip/hip_runtime.h>
#include <stdint.h>

typedef int   int4v __attribute__((ext_vector_type(4)));
typedef float f32x4 __attribute__((ext_vector_type(4)));

// ---- workspace layout (bytes) ----
#define WS_SCALES 0ull
#define WS_ZERO   256ull
#define WS_BI1    1024ull
#define WS_BI2    2048ull
#define WS_BI3    4096ull
#define WS_BIS    8192ull
#define WS_W1Q    16384ull                     // int8 [256][512]
#define WS_W2Q    (WS_W1Q + 131072ull)         // int8 [256][2304]  k=(kh*3+kw)*256+c
#define WS_W3Q    (WS_W2Q + 589824ull)         // int8 [1024][256]
#define WS_WSQ    (WS_W3Q + 262144ull)         // int8 [1024][512]
#define WS_A0     2097152ull                   // int8 [50176][512]  (= [64][784][512])
#define WS_A1     (WS_A0 + 25690112ull)        // int8 [50176][256]
#define WS_A2     (WS_A1 + 12845056ull)        // int8 [12544][256]  (= [64][196][256])

__global__ void k_init(float* wshead) {
    int i = blockIdx.x * 256 + threadIdx.x;
    wshead[i] = 0.0f;   // 16 blocks x 256 = 16 KB: scales+zero page+biases
}

__global__ void k_maxabs(const float* __restrict__ w1, const float* __restrict__ w2,
                         const float* __restrict__ w3, const float* __restrict__ wsd,
                         float* __restrict__ scales) {
    const float* srcs[4] = {w1, w2, w3, wsd};
    const int ns[4] = {131072, 589824, 262144, 524288};
    int t = blockIdx.y;
    const float* s = srcs[t];
    int n = ns[t];
    float m = 0.0f;
    for (int i = blockIdx.x * 256 + threadIdx.x; i < n; i += gridDim.x * 256)
        m = fmaxf(m, fabsf(s[i]));
    __shared__ float red[256];
    red[threadIdx.x] = m;
    __syncthreads();
    for (int st = 128; st > 0; st >>= 1) {
        if (threadIdx.x < st) red[threadIdx.x] = fmaxf(red[threadIdx.x], red[threadIdx.x + st]);
        __syncthreads();
    }
    if (threadIdx.x == 0) atomicMax((int*)&scales[t], __float_as_int(red[0]));
}

__global__ void k_quant_w(const float* __restrict__ w1, const float* __restrict__ w2,
                          const float* __restrict__ w3, const float* __restrict__ wsd,
                          const float* __restrict__ b1, const float* __restrict__ b2,
                          const float* __restrict__ b3, const float* __restrict__ bs,
                          char* __restrict__ wsb) {
    const float* sc = (const float*)(wsb + WS_SCALES);
    int mode = blockIdx.y;
    int i0 = blockIdx.x * 256 + threadIdx.x;
    int stride = gridDim.x * 256;
    if (mode == 0) {
        float s = sc[0]; signed char* o = (signed char*)(wsb + WS_W1Q);
        for (int i = i0; i < 131072; i += stride)
            o[i] = (signed char)(int)rintf(fminf(fmaxf(w1[i] / s, -1.f), 1.f) * 127.f);
    } else if (mode == 1) {
        float s = sc[1]; signed char* o = (signed char*)(wsb + WS_W2Q);
        for (int i = i0; i < 589824; i += stride) {
            int oo = i / 2304, r2 = i - oo * 2304;
            int c = r2 / 9, kk = r2 - c * 9;
            o[(size_t)oo * 2304 + kk * 256 + c] =
                (signed char)(int)rintf(fminf(fmaxf(w2[i] / s, -1.f), 1.f) * 127.f);
        }
    } else if (mode == 2) {
        float s = sc[2]; signed char* o = (signed char*)(wsb + WS_W3Q);
        for (int i = i0; i < 262144; i += stride)
            o[i] = (signed char)(int)rintf(fminf(fmaxf(w3[i] / s, -1.f), 1.f) * 127.f);
    } else if (mode == 3) {
        float s = sc[3]; signed char* o = (signed char*)(wsb + WS_WSQ);
        for (int i = i0; i < 524288; i += stride)
            o[i] = (signed char)(int)rintf(fminf(fmaxf(wsd[i] / s, -1.f), 1.f) * 127.f);
    } else if (mode == 4) {
        float* o = (float*)(wsb + WS_BI1);
        for (int i = i0; i < 256; i += stride) o[i] = rintf(b1[i] * 127.f);
    } else if (mode == 5) {
        float* o = (float*)(wsb + WS_BI2);
        for (int i = i0; i < 256; i += stride) o[i] = rintf(b2[i] * 127.f);
    } else if (mode == 6) {
        float* o = (float*)(wsb + WS_BI3);
        for (int i = i0; i < 1024; i += stride) o[i] = rintf(b3[i] * 127.f);
    } else {
        float* o = (float*)(wsb + WS_BIS);
        for (int i = i0; i < 1024; i += stride) o[i] = rintf(bs[i] * 127.f);
    }
}

// quantize + transpose x: float [64][512][784] -> int8 a0 [64*784][512]
__global__ void k_quant_x(const float* __restrict__ x, signed char* __restrict__ a0) {
    __shared__ signed char tile[32][33];
    int b = blockIdx.z;
    int p0 = blockIdx.x * 32, c0 = blockIdx.y * 32;
    int tp = threadIdx.x & 31, tr = threadIdx.x >> 5;
    const float* xb = x + ((size_t)b * 512 + c0) * 784 + p0;
    for (int i = 0; i < 4; i++) {
        int cc = tr + i * 8;
        float v = (p0 + tp < 784) ? xb[(size_t)cc * 784 + tp] : 0.f;
        v = fminf(fmaxf(v * 2.f, -1.f), 1.f);
        tile[cc][tp] = (signed char)(int)rintf(v * 127.f);
    }
    __syncthreads();
    // out: 4 consecutive c per thread -> 4B stores, 32B contiguous per 8 lanes
    int pp = threadIdx.x >> 3, cs = (threadIdx.x & 7) * 4;
    if (p0 + pp < 784) {
        unsigned pk = 0;
        for (int i = 0; i < 4; i++)
            pk |= (unsigned)(unsigned char)tile[cs + i][pp] << (8 * i);
        *(unsigned*)(a0 + ((size_t)b * 784 + p0 + pp) * 512 + c0 + cs) = pk;
    }
}

// ---------- i8-MFMA GEMM kernels ----------
// MODE 0: conv1  M=256 K=512  Nflat=50176 -> a1 int8 [n][256]
// MODE 1: conv2  M=256 K=2304 Nflat=12544 (im2col 3x3/s2/p1 gather) -> a2 int8 [n][256]
// MODE 2: conv3 (t<4: K=256 a2) + shortcut (t>=4: K=512 a0 strided) -> float out NCHW
template <int MODE, int BM, int BN, int WGM, int WGN>
__global__ __launch_bounds__(256) void k_conv(char* __restrict__ wsb, float* __restrict__ dout) {
    constexpr int FM = BM / WGM / 16;
    constexpr int FN = BN / WGN / 16;
    constexpr int ISS_A = BM / 16;
    constexpr int NISS = (BM + BN) / 16;
    constexpr int NI = NISS / 4;
    constexpr int KTOT = (MODE == 0) ? 512 : (MODE == 1) ? 2304 : 768;
    constexpr int NSTEP = KTOT / 64;
    constexpr int BMP = BM + 16;                     // padded epi stride (int8 modes)
    constexpr int LDS_STAGE = (BM + BN) * 64;
    constexpr int LDS_EPI = (MODE == 2) ? 64 * 68 * 4 : BN * BMP;
    constexpr int LDSZ = LDS_STAGE > LDS_EPI ? LDS_STAGE : LDS_EPI;

    __shared__ alignas(16) char lds[LDSZ];

    const int tid = threadIdx.x;
    const int wid = tid >> 6;
    const int lane = tid & 63;
    const int n0 = blockIdx.x * BN;
    const int m0 = blockIdx.y * BM;
    const int bb = blockIdx.z;

    const float* sc = (const float*)(wsb + WS_SCALES);
    const int srow = lane >> 2;
    const int schunk = lane & 3;
    const int lrow = lane & 15;
    const int quad = lane >> 4;
    const int wm = (wid % WGM) * (BM / WGM);
    const int wn = (wid / WGM) * (BN / WGN);
    const char* zp = wsb + WS_ZERO + schunk * 16;

    int4v acc3[FM][FN] = {};
    int4v accS[FM][FN] = {};

    for (int t = 0; t < NSTEP; ++t) {
        const int k0 = t * 64;
        uint4 stg[NI];
#pragma unroll
        for (int ii = 0; ii < NI; ii++) {
            const int s = wid + ii * 4;
            const char* g;
            if (s < ISS_A) {
                int m = m0 + s * 16 + srow;
                if (MODE == 0)
                    g = wsb + WS_W1Q + (size_t)m * 512 + k0 + schunk * 16;
                else if (MODE == 1)
                    g = wsb + WS_W2Q + (size_t)m * 2304 + k0 + schunk * 16;
                else
                    g = (k0 < 256) ? wsb + WS_W3Q + (size_t)m * 256 + k0 + schunk * 16
                                   : wsb + WS_WSQ + (size_t)m * 512 + (k0 - 256) + schunk * 16;
            } else {
                int n = n0 + (s - ISS_A) * 16 + srow;
                g = zp;
                if (MODE == 0) {
                    g = wsb + WS_A0 + (size_t)n * 512 + k0 + schunk * 16;
                } else if (MODE == 1) {
                    unsigned b = (unsigned)n / 196u;
                    unsigned hw = (unsigned)n - b * 196u;
                    int oh = hw / 14, ow = hw - oh * 14;
                    int tap = k0 >> 8;
                    int kh = tap / 3, kw = tap - kh * 3;
                    int c0 = k0 & 255;
                    int ih = 2 * oh - 1 + kh, iw = 2 * ow - 1 + kw;
                    if (ih >= 0 && ih < 28 && iw >= 0 && iw < 28)
                        g = wsb + WS_A1 + ((size_t)b * 784 + ih * 28 + iw) * 256 + c0 + schunk * 16;
                } else {
                    if (n < 196) {
                        if (k0 < 256) {
                            g = wsb + WS_A2 + ((size_t)bb * 196 + n) * 256 + k0 + schunk * 16;
                        } else {
                            int oh = n / 14, ow = n - oh * 14;
                            int ps = oh * 56 + ow * 2;
                            g = wsb + WS_A0 + ((size_t)bb * 784 + ps) * 512 + (k0 - 256) + schunk * 16;
                        }
                    }
                }
            }
            stg[ii] = *(const uint4*)g;
        }
        __syncthreads();
#pragma unroll
        for (int ii = 0; ii < NI; ii++) {
            const int s = wid + ii * 4;
            const int r = s * 16 + srow;
            const int pc = schunk ^ ((r >> 1) & 3);
            *(uint4*)(lds + r * 64 + pc * 16) = stg[ii];
        }
        __syncthreads();

        int4v afr[FM], bfr[FN];
#pragma unroll
        for (int i = 0; i < FM; i++) {
            int m = wm + i * 16 + lrow;
            afr[i] = *(const int4v*)(lds + m * 64 + ((quad ^ ((m >> 1) & 3)) << 4));
        }
#pragma unroll
        for (int j = 0; j < FN; j++) {
            int n = wn + j * 16 + lrow;
            bfr[j] = *(const int4v*)(lds + (BM + n) * 64 + ((quad ^ ((n >> 1) & 3)) << 4));
        }
        if (MODE != 2 || t < 4) {
#pragma unroll
            for (int i = 0; i < FM; i++)
#pragma unroll
                for (int j = 0; j < FN; j++)
                    acc3[i][j] = __builtin_amdgcn_mfma_i32_16x16x64_i8(afr[i], bfr[j], acc3[i][j], 0, 0, 0);
        } else {
#pragma unroll
            for (int i = 0; i < FM; i++)
#pragma unroll
                for (int j = 0; j < FN; j++)
                    accS[i][j] = __builtin_amdgcn_mfma_i32_16x16x64_i8(afr[i], bfr[j], accS[i][j], 0, 0, 0);
        }
    }

    // ---------------- epilogue (C/D map: col=lane&15, row=quad*4+reg) ----------------
    if (MODE == 0 || MODE == 1) {
        const float alpha = sc[MODE] / 16129.0f;
        const float* bi = (const float*)(wsb + (MODE == 0 ? WS_BI1 : WS_BI2));
        signed char* outp = (signed char*)(wsb + (MODE == 0 ? WS_A1 : WS_A2));
        __syncthreads();   // staging reads finished everywhere
#pragma unroll
        for (int i = 0; i < FM; i++) {
            int mloc = wm + i * 16 + quad * 4;      // local m of r=0
            int mb = m0 + mloc;
            float bt[4];
#pragma unroll
            for (int r = 0; r < 4; r++) bt[r] = bi[mb + r] * (2.0f / 127.0f);
#pragma unroll
            for (int j = 0; j < FN; j++) {
                int nloc = wn + j * 16 + lrow;
                unsigned pk = 0;
#pragma unroll
                for (int r = 0; r < 4; r++) {
                    float v = alpha * (float)acc3[i][j][r] + bt[r];
                    int q = (int)rintf(127.0f * fminf(fmaxf(2.0f * v, 0.0f), 1.0f));
                    pk |= (unsigned)(q & 0xFF) << (8 * r);
                }
                *(unsigned*)(lds + nloc * BMP + mloc) = pk;
            }
        }
        __syncthreads();
        // coalesced copy-out: full 64B-line coverage, rows are [n][256] m-contig
        for (int u = tid; u < BN * (BM / 16); u += 256) {
            int row = u / (BM / 16);
            int seg = u % (BM / 16);
            uint4 v = *(const uint4*)(lds + row * BMP + seg * 16);
            *(uint4*)(outp + (size_t)(n0 + row) * 256 + m0 + seg * 16) = v;
        }
    } else {
        const float c2 = sc[1], c3 = sc[2], cS = sc[3];
        const float* bi3 = (const float*)(wsb + WS_BI3);
        const float* bis = (const float*)(wsb + WS_BIS);
        float* ldsF = (float*)lds;
        for (int half = 0; half < 2; half++) {
            __syncthreads();
            if (wm == half * 64) {
#pragma unroll
                for (int i = 0; i < FM; i++) {
                    int mloc = i * 16 + quad * 4;           // within half [0,64)
                    int mg = m0 + half * 64 + mloc;         // global m
                    float bt[4];
#pragma unroll
                    for (int r = 0; r < 4; r++)
                        bt[r] = bi3[mg + r] * (c3 / (127.0f * c2)) + bis[mg + r] * (1.0f / 127.0f);
#pragma unroll
                    for (int j = 0; j < FN; j++) {
                        int nloc = wn + j * 16 + lrow;
#pragma unroll
                        for (int r = 0; r < 4; r++) {
                            float v = (c3 * (float)acc3[i][j][r] + cS * (float)accS[i][j][r])
                                          * (0.5f / 16129.0f) + bt[r];
                            v = v < 0.0f ? 0.0f : (v > 6.0f ? 6.0f : v);  // NaN-propagating
                            ldsF[(mloc + r) * 68 + nloc] = v;
                        }
                    }
                }
            }
            __syncthreads();
            // copy out 64 rows x 64 floats (aligned 16B segments along n)
            if (tid < 256) {
                int row = tid >> 2, seg = tid & 3;
                int nbase = n0 + seg * 16;
                const float* src = ldsF + row * 68 + seg * 16;
                float* dst = dout + ((size_t)bb * 1024 + m0 + half * 64 + row) * 196 + nbase;
                if (nbase + 16 <= 196) {
                    *(f32x4*)(dst + 0)  = *(const f32x4*)(src + 0);
                    *(f32x4*)(dst + 4)  = *(const f32x4*)(src + 4);
                    *(f32x4*)(dst + 8)  = *(const f32x4*)(src + 8);
                    *(f32x4*)(dst + 12) = *(const f32x4*)(src + 12);
                } else {
                    for (int q = 0; q < 16 && nbase + q < 196; q++) dst[q] = src[q];
                }
            }
        }
    }
}

extern "C" void kernel_launch(void* const* d_in, const int* in_sizes, int n_in,
                              void* d_out, int out_size, void* d_ws, size_t ws_size,
                              hipStream_t stream) {
    const float* x   = (const float*)d_in[0];
    const float* w1  = (const float*)d_in[1];
    const float* b1  = (const float*)d_in[2];
    const float* w2  = (const float*)d_in[3];
    const float* b2  = (const float*)d_in[4];
    const float* w3  = (const float*)d_in[5];
    const float* b3  = (const float*)d_in[6];
    const float* wsd = (const float*)d_in[7];
    const float* bs  = (const float*)d_in[8];
    float* out = (float*)d_out;
    char* wsb = (char*)d_ws;

    k_init<<<16, 256, 0, stream>>>((float*)wsb);
    k_maxabs<<<dim3(32, 4), 256, 0, stream>>>(w1, w2, w3, wsd, (float*)(wsb + WS_SCALES));
    k_quant_w<<<dim3(96, 8), 256, 0, stream>>>(w1, w2, w3, wsd, b1, b2, b3, bs, wsb);
    k_quant_x<<<dim3(25, 16, 64), 256, 0, stream>>>(x, (signed char*)(wsb + WS_A0));
    k_conv<0, 128, 64, 2, 2><<<dim3(784, 2, 1), 256, 0, stream>>>(wsb, out);   // conv1
    k_conv<1, 64, 64, 2, 2><<<dim3(196, 4, 1), 256, 0, stream>>>(wsb, out);    // conv2
    k_conv<2, 128, 64, 2, 2><<<dim3(4, 8, 64), 256, 0, stream>>>(wsb, out);    // conv3+sc
}